// Round 8
// baseline (4051.383 us; speedup 1.0000x reference)
//
#include <hip/hip_runtime.h>
#include <stdint.h>

// Problem constants
#define B_ 32
#define T_ 2048
#define D_ 512
#define N_ 512
#define NG 2048   // 4 gates * N

typedef _Float16 f16;
typedef _Float16 half2v __attribute__((ext_vector_type(2)));
typedef _Float16 half8  __attribute__((ext_vector_type(8)));
typedef float    float4v __attribute__((ext_vector_type(4)));
typedef unsigned long long u64;

union U32H2 { unsigned u; half2v h; };
union U4H8  { uint4 u; half8 h; };
union H16U  { f16 h; unsigned short s; };

static __device__ __forceinline__ float fast_sigmoid(float x) {
    return __builtin_amdgcn_rcpf(1.f + __expf(-x));
}
static __device__ __forceinline__ float fast_tanh(float x) {
    // 1 - 2/(1+e^{2x}): correct limits at +/-inf, no clamp needed
    return 1.f - 2.f * __builtin_amdgcn_rcpf(1.f + __expf(2.f * x));
}

// ---------------- prep: cast x (f32) -> f16 ----------------
__global__ void prep_cast(const float* __restrict__ x, f16* __restrict__ x16) {
    long i = ((long)blockIdx.x * 256 + threadIdx.x) * 4;
    float4 v = *(const float4*)(x + i);
    union { f16 h[4]; uint2 u; } pk;
    pk.h[0] = (f16)v.x; pk.h[1] = (f16)v.y; pk.h[2] = (f16)v.z; pk.h[3] = (f16)v.w;
    *(uint2*)(x16 + i) = pk.u;
}

// ---------------- prep: transpose+cast weights, biases ----------------
__global__ void prep_w(const float* __restrict__ Wi, const float* __restrict__ Ui,
                       const float* __restrict__ Wf, const float* __restrict__ Uf,
                       const float* __restrict__ Wg, const float* __restrict__ Ug,
                       const float* __restrict__ Wc, const float* __restrict__ Uc,
                       const float* __restrict__ Wo,
                       const float* __restrict__ bi, const float* __restrict__ bff,
                       const float* __restrict__ bg, const float* __restrict__ bc,
                       f16* __restrict__ wt, f16* __restrict__ ut,
                       f16* __restrict__ wot, float* __restrict__ bias)
{
    const int y = blockIdx.y;
    const int e = blockIdx.x * 256 + threadIdx.x;   // 0..262143
    if (y < 4) {
        const float* src = (y == 0) ? Wi : (y == 1) ? Wf : (y == 2) ? Wg : Wc;
        int col = e >> 9, d = e & 511;
        wt[(long)y * 512 * 512 + e] = (f16)src[(long)d * 512 + col];   // wt[(g*512+col)][d]
    } else if (y < 8) {
        const float* src = (y == 4) ? Ui : (y == 5) ? Uf : (y == 6) ? Ug : Uc;
        int col = e >> 9, d = e & 511;
        ut[(long)(y - 4) * 512 * 512 + e] = (f16)src[(long)d * 512 + col];
    } else if (y == 8) {
        int col = e >> 9, d = e & 511;
        wot[e] = (f16)Wo[(long)d * 512 + col];
    } else {
        if (e < 2048) {
            const float* bsrc = (e < 512) ? bi : (e < 1024) ? bff : (e < 1536) ? bg : bc;
            bias[e] = bsrc[e & 511];
        }
    }
}

// ---------------- phase 1: xpre[b][t][2048] = x @ [Wi|Wf|Wg|Wc] + bias (f16 out) ----------------
__launch_bounds__(256)
__global__ void gemm_xw(const f16* __restrict__ A, const f16* __restrict__ Bt,
                        const float* __restrict__ bias, f16* __restrict__ C)
{
    __shared__ f16 sA[128 * 32];
    __shared__ f16 sB[128 * 32];
    const int tid = threadIdx.x;
    const int m0 = blockIdx.y * 128;
    const int n0 = blockIdx.x * 128;
    const int wave = tid >> 6, lane = tid & 63;
    const int wm = wave >> 1, wn = wave & 1;
    const int lrow = lane & 15, quad = lane >> 4;

    float4v acc[4][4];
#pragma unroll
    for (int i = 0; i < 4; i++)
#pragma unroll
        for (int j = 0; j < 4; j++) acc[i][j] = (float4v){0.f, 0.f, 0.f, 0.f};

    const int srow = tid >> 2;        // 0..63
    const int sk8 = (tid & 3) * 8;    // 0,8,16,24

    for (int k0 = 0; k0 < 512; k0 += 32) {
#pragma unroll
        for (int rr = 0; rr < 128; rr += 64) {
            const int row = rr + srow;
            *(uint4*)&sA[row * 32 + sk8] = *(const uint4*)&A[(long)(m0 + row) * 512 + k0 + sk8];
            *(uint4*)&sB[row * 32 + sk8] = *(const uint4*)&Bt[(long)(n0 + row) * 512 + k0 + sk8];
        }
        __syncthreads();
        half8 af[4], bf[4];
#pragma unroll
        for (int mi = 0; mi < 4; mi++)
            af[mi] = *(half8*)&sA[(wm * 64 + mi * 16 + lrow) * 32 + quad * 8];
#pragma unroll
        for (int ni = 0; ni < 4; ni++)
            bf[ni] = *(half8*)&sB[(wn * 64 + ni * 16 + lrow) * 32 + quad * 8];
#pragma unroll
        for (int mi = 0; mi < 4; mi++)
#pragma unroll
            for (int ni = 0; ni < 4; ni++)
                acc[mi][ni] = __builtin_amdgcn_mfma_f32_16x16x32_f16(af[mi], bf[ni], acc[mi][ni], 0, 0, 0);
        __syncthreads();
    }
#pragma unroll
    for (int mi = 0; mi < 4; mi++)
#pragma unroll
        for (int ni = 0; ni < 4; ni++)
#pragma unroll
            for (int r = 0; r < 4; r++) {
                int m = m0 + wm * 64 + mi * 16 + quad * 4 + r;
                int n = n0 + wn * 64 + ni * 16 + lrow;
                C[(long)m * NG + n] = (f16)(acc[mi][ni][r] + bias[n]);
            }
}

// ---------------- phase 3: out[b][t][n] = relu(hs @ Wo + bo) (f32 out, row remap) ----------------
__launch_bounds__(256)
__global__ void gemm_hw(const f16* __restrict__ A, const f16* __restrict__ Bt,
                        const float* __restrict__ bias, float* __restrict__ out)
{
    __shared__ f16 sA[128 * 32];
    __shared__ f16 sB[128 * 32];
    const int tid = threadIdx.x;
    const int m0 = blockIdx.y * 128;
    const int n0 = blockIdx.x * 128;
    const int wave = tid >> 6, lane = tid & 63;
    const int wm = wave >> 1, wn = wave & 1;
    const int lrow = lane & 15, quad = lane >> 4;

    float4v acc[4][4];
#pragma unroll
    for (int i = 0; i < 4; i++)
#pragma unroll
        for (int j = 0; j < 4; j++) acc[i][j] = (float4v){0.f, 0.f, 0.f, 0.f};

    const int srow = tid >> 2;
    const int sk8 = (tid & 3) * 8;

    for (int k0 = 0; k0 < 512; k0 += 32) {
#pragma unroll
        for (int rr = 0; rr < 128; rr += 64) {
            const int row = rr + srow;
            *(uint4*)&sA[row * 32 + sk8] = *(const uint4*)&A[(long)(m0 + row) * 512 + k0 + sk8];
            *(uint4*)&sB[row * 32 + sk8] = *(const uint4*)&Bt[(long)(n0 + row) * 512 + k0 + sk8];
        }
        __syncthreads();
        half8 af[4], bf[4];
#pragma unroll
        for (int mi = 0; mi < 4; mi++)
            af[mi] = *(half8*)&sA[(wm * 64 + mi * 16 + lrow) * 32 + quad * 8];
#pragma unroll
        for (int ni = 0; ni < 4; ni++)
            bf[ni] = *(half8*)&sB[(wn * 64 + ni * 16 + lrow) * 32 + quad * 8];
#pragma unroll
        for (int mi = 0; mi < 4; mi++)
#pragma unroll
            for (int ni = 0; ni < 4; ni++)
                acc[mi][ni] = __builtin_amdgcn_mfma_f32_16x16x32_f16(af[mi], bf[ni], acc[mi][ni], 0, 0, 0);
        __syncthreads();
    }
#pragma unroll
    for (int mi = 0; mi < 4; mi++)
#pragma unroll
        for (int ni = 0; ni < 4; ni++)
#pragma unroll
            for (int r = 0; r < 4; r++) {
                int m = m0 + wm * 64 + mi * 16 + quad * 4 + r;   // m = t*B + b
                int n = n0 + wn * 64 + ni * 16 + lrow;
                float v = acc[mi][ni][r] + bias[n];
                v = fmaxf(v, 0.f);
                int t = m >> 5, b = m & 31;
                out[(long)b * (T_ * (long)N_) + (long)t * N_ + n] = v;
            }
}

// ---------------- phase 2: the recurrence (2-batch rings x 16 blocks) ----------------
// Counter arithmetic on R7 (3856 cy/step): MfmaUtil 27.6% -> matrix pipe busy
// ~1100 cy/step, SERIAL between the two barriers -- the largest single
// component, and it's 16x row-replication waste. Fix: 16 rings of 2 batches;
// the MFMA A-operand's 16 M-rows carry BOTH batches (rows 0-7 = batch0's h,
// rows 8-15 = batch1's; A row = lane&15 so each lane selects its batch via
// (lane&15)>>3 -- layout verified against gemm_xw's working fragment map).
// 16 blocks/ring, each owning e-cols [32s,32s+32) x 4 gates = 128 gate-cols
// for both batches: 8 waves x 16 MFMA = 128 MFMA/CU/step -> matrix phase
// ~620 cy (half of R7). bid = s*16 + r => ring blocks all ≡ r (mod 8) -> same
// XCD; 2 rings/XCD x 16 blocks = 32 CUs/XCD, exact chip fit.
// Handoff protocol IDENTICAL in form to R2/R7 (best measured): tagged u64,
// relaxed agent atomics, parity double-buffer, one-slot-per-thread coalesced
// poll (all 8 waves poll the ring's 512 slots), s_sleep retry, raw barriers
// (lgkmcnt-only). Safety: producer overwrites a parity-p slot (tag t+2 over
// tag t) only after its block observed tag t+1 on all polled slots, which via
// the in-block barriers requires every peer block to have passed the barrier
// following its tag-t reads.
__launch_bounds__(512, 2)
__global__ void lstm_rec(const f16* __restrict__ Ut,      // [2048 cols][512 rows] f16
                         const f16* __restrict__ xpre,    // [B][T][2048] f16
                         u64* __restrict__ hg64,          // [2][16 rings][2 b][256] tagged h pairs
                         unsigned* __restrict__ hs32,     // [T][B][256] u32 (packed f16x2)
                         int unused)
{
    const int bid = blockIdx.x;
    const int r = bid & 15;           // ring: batches {2r, 2r+1}
    const int s = bid >> 4;           // 0..15: e-slice [32s, 32s+32)
    const int tid = threadIdx.x;      // 0..511
    const int w    = tid >> 6;        // wave 0..7
    const int lane = tid & 63;
    const int quad = lane >> 4;
    const int lcol = lane & 15;
    const int g0   = w >> 1;          // gate of this wave's col-tile
    const int half = w & 1;           // which 16-col half of the 32-col slice

    __shared__ __align__(16) unsigned hbuf[512];   // [2 batches][256 dw] packed h
    __shared__ float prelds[256];                  // [2 batches][4 g][32 e]

    // ---- persistent B-fragments: 16 cols (g0, half) x 16 K-steps = 64 VGPR ----
    half8 bfr[16];
    {
        const f16* bp = Ut + (long)(g0 * 512 + s * 32 + half * 16 + lcol) * 512 + quad * 8;
#pragma unroll
        for (int ks = 0; ks < 16; ks++)
            bfr[ks] = *(const half8*)(bp + ks * 32);
    }

    hbuf[tid] = 0u;                   // h_{-1} = 0 (512 dwords, all threads)
    float cst = 0.f;                  // valid for tid<64: c-state of (batch, e)
    __syncthreads();                  // prologue full sync

    // gate-thread identity (tid<64): batch = tid>>5, e = tid&31
    const int gbatch = tid >> 5;
    const int ge = tid & 31;
    const long bglob = 2L * r + gbatch;
    const f16* xb = xpre + bglob * T_ * NG + s * 32 + ge;   // deref only when tid<64

    // preload xpre for t=0
    f16 xc_i = (f16)0, xc_f = (f16)0, xc_g = (f16)0, xc_c = (f16)0;
    if (tid < 64) {
        xc_i = xb[0]; xc_f = xb[512]; xc_g = xb[1024]; xc_c = xb[1536];
    }

    // A-fragment source: row = lane&15 -> batch (lcol>>3); k-slice by quad
    const unsigned aoff = (unsigned)((lcol >> 3) * 256 + quad * 4);

    for (int t = 0; t < T_; ++t) {
        // ---- acquire h_{t-1}: all 8 waves poll the ring's 512 slots ----
        if (t > 0) {
            const u64* slot = hg64 + (size_t)(t & 1) * 8192 + (size_t)r * 512 + tid;
            const unsigned tag = (unsigned)t;
            u64 v;
            while ((unsigned)((v = __hip_atomic_load(slot, __ATOMIC_RELAXED,
                                                     __HIP_MEMORY_SCOPE_AGENT)) >> 32) != tag)
                __builtin_amdgcn_s_sleep(1);
            hbuf[tid] = (unsigned)v;
        }
        asm volatile("" ::: "memory");
        __builtin_amdgcn_sched_barrier(0);

        // ---- xpre prefetch for t+1 (consumed next iteration's gates) ----
        f16 xn_i = (f16)0, xn_f = (f16)0, xn_g = (f16)0, xn_c = (f16)0;
        if (t < T_ - 1 && tid < 64) {
            const f16* p = xb + (long)(t + 1) * NG;
            xn_i = p[0]; xn_f = p[512]; xn_g = p[1024]; xn_c = p[1536];
        }

        // ---- barrier 1: publish hbuf (LDS only; no vmcnt drain) ----
        asm volatile("s_waitcnt lgkmcnt(0)" ::: "memory");
        __builtin_amdgcn_s_barrier();
        __builtin_amdgcn_sched_barrier(0);

        // ---- h @ U via MFMA: A rows = {8x batch0 h, 8x batch1 h} ----
        float4v ac0 = {0.f,0.f,0.f,0.f}, ac1 = {0.f,0.f,0.f,0.f};
        float4v ac2 = {0.f,0.f,0.f,0.f}, ac3 = {0.f,0.f,0.f,0.f};
#pragma unroll
        for (int ks = 0; ks < 16; ks += 4) {
            U4H8 a0, a1, a2, a3;
            a0.u = *(const uint4*)&hbuf[aoff + (ks + 0) * 16];
            a1.u = *(const uint4*)&hbuf[aoff + (ks + 1) * 16];
            a2.u = *(const uint4*)&hbuf[aoff + (ks + 2) * 16];
            a3.u = *(const uint4*)&hbuf[aoff + (ks + 3) * 16];
            ac0 = __builtin_amdgcn_mfma_f32_16x16x32_f16(a0.h, bfr[ks + 0], ac0, 0, 0, 0);
            ac1 = __builtin_amdgcn_mfma_f32_16x16x32_f16(a1.h, bfr[ks + 1], ac1, 0, 0, 0);
            ac2 = __builtin_amdgcn_mfma_f32_16x16x32_f16(a2.h, bfr[ks + 2], ac2, 0, 0, 0);
            ac3 = __builtin_amdgcn_mfma_f32_16x16x32_f16(a3.h, bfr[ks + 3], ac3, 0, 0, 0);
        }
        // C row = quad*4 + reg; reg0 of quad0 = row 0 (batch0), of quad2 = row 8 (batch1)
        if ((quad & 1) == 0)
            prelds[(quad >> 1) * 128 + g0 * 32 + half * 16 + lcol] =
                (ac0[0] + ac1[0]) + (ac2[0] + ac3[0]);

        // ---- barrier 2: publish prelds (LDS only; no vmcnt drain) ----
        asm volatile("s_waitcnt lgkmcnt(0)" ::: "memory");
        __builtin_amdgcn_s_barrier();
        __builtin_amdgcn_sched_barrier(0);

        // ---- gates: 64 lanes = 2 batches x 32 e-cols, one column each ----
        if (tid < 64) {
            float pre_i = prelds[gbatch * 128 +       ge] + (float)xc_i;
            float pre_f = prelds[gbatch * 128 +  32 + ge] + (float)xc_f;
            float pre_g = prelds[gbatch * 128 +  64 + ge] + (float)xc_g;
            float pre_c = prelds[gbatch * 128 +  96 + ge] + (float)xc_c;
            float gi = fast_sigmoid(pre_i);
            float gf = fast_sigmoid(pre_f);
            float gg = fast_sigmoid(pre_g);
            float ct = fast_tanh(pre_c);
            cst = gf * cst + gi * ct;
            float h = gg * fast_tanh(cst);

            // pack pairs within wave 0: lanes 0-15 -> batch0 pairs, 32-47 -> batch1
            H16U cv; cv.h = (f16)h;
            unsigned hx = (unsigned)cv.s;
            const int base = lane & 32;
            const int j = lane & 15;
            unsigned lo = __shfl(hx, base + 2 * j);
            unsigned hi = __shfl(hx, base + 2 * j + 1);
            if ((lane & 31) < 16) {
                const int pb = lane >> 5;             // batch
                unsigned pk = lo | (hi << 16);
                u64 pv = ((u64)(unsigned)(t + 1) << 32) | (u64)pk;
                __hip_atomic_store(hg64 + (size_t)((t + 1) & 1) * 8192 + (size_t)r * 512
                                        + (size_t)pb * 256 + s * 16 + j,
                                   pv, __ATOMIC_RELAXED, __HIP_MEMORY_SCOPE_AGENT);
                // history for gemm_hw (not on critical path)
                hs32[((long)t * B_ + (2 * r + pb)) * 256 + s * 16 + j] = pk;
            }
        }
        // rotate xpre pipeline registers
        xc_i = xn_i; xc_f = xn_f; xc_g = xn_g; xc_c = xn_c;
        // no trailing barrier: next iteration's poll + barrier provide ordering
    }
}

// ---------------- launch ----------------
extern "C" void kernel_launch(void* const* d_in, const int* in_sizes, int n_in,
                              void* d_out, int out_size, void* d_ws, size_t ws_size,
                              hipStream_t stream)
{
    const float* x  = (const float*)d_in[0];
    const float* Wi = (const float*)d_in[1];
    const float* Ui = (const float*)d_in[2];
    const float* Wf = (const float*)d_in[3];
    const float* Uf = (const float*)d_in[4];
    const float* Wg = (const float*)d_in[5];
    const float* Ug = (const float*)d_in[6];
    const float* Wc = (const float*)d_in[7];
    const float* Uc = (const float*)d_in[8];
    const float* Wo = (const float*)d_in[9];
    const float* bi = (const float*)d_in[10];
    const float* bf = (const float*)d_in[11];
    const float* bg = (const float*)d_in[12];
    const float* bc = (const float*)d_in[13];
    const float* bo = (const float*)d_in[14];

    char* ws = (char*)d_ws;
    f16*      x16   = (f16*)(ws + 0L);            // 64 MB
    f16*      xpre  = (f16*)(ws + 67108864L);     // 256 MB
    f16*      hs    = (f16*)(ws + 335544320L);    // 64 MB
    f16*      wt    = (f16*)(ws + 402653184L);    // 2 MB
    f16*      ut    = (f16*)(ws + 404750336L);    // 2 MB
    f16*      wot   = (f16*)(ws + 406847488L);    // 0.5 MB
    float*    bias  = (float*)(ws + 407371776L);  // 8 KB
    u64*      hg64  = (u64*)(ws + 407379968L);    // 128 KB tagged h exchange
    // hg64 is re-poisoned to 0xAA each call -> tag 0xAAAAAAAA never matches a
    // real t in [1,2048], so stale data cannot satisfy a poll.

    prep_cast<<<dim3(32768), dim3(256), 0, stream>>>(x, x16);
    prep_w<<<dim3(1024, 10), dim3(256), 0, stream>>>(Wi, Ui, Wf, Uf, Wg, Ug, Wc, Uc, Wo,
                                                     bi, bf, bg, bc, wt, ut, wot, bias);
    gemm_xw<<<dim3(16, 512), dim3(256), 0, stream>>>(x16, wt, bias, xpre);
    lstm_rec<<<dim3(256), dim3(512), 0, stream>>>(ut, xpre, hg64, (unsigned*)hs, 0);
    gemm_hw<<<dim3(4, 512), dim3(256), 0, stream>>>(hs, wot, bo, (float*)d_out);
}